// Round 4
// baseline (3248.557 us; speedup 1.0000x reference)
//
#include <hip/hip_runtime.h>
#include <stdint.h>

#define IN_F   512
#define OUT_F  512
#define BATCH  512
#define NWG    32
#define TPB    256
#define BAND   16   // NWG*BAND == OUT_F

#define SENT 0xFFFFFFFFu

__device__ __forceinline__ float4 ld4(const float* p) {
    return *reinterpret_cast<const float4*>(p);
}
__device__ __forceinline__ float clmp1(float v) {
    return fminf(1.0f, fmaxf(-1.0f, v));
}
__device__ __forceinline__ float wsum64(float v) {
#pragma unroll
    for (int o = 32; o > 0; o >>= 1) v += __shfl_xor(v, o);
    return v;
}
__device__ __forceinline__ float wmax64(float v) {
#pragma unroll
    for (int o = 32; o > 0; o >>= 1) v = fmaxf(v, __shfl_xor(v, o));
    return v;
}
__device__ __forceinline__ float wmin64(float v) {
#pragma unroll
    for (int o = 32; o > 0; o >>= 1) v = fminf(v, __shfl_xor(v, o));
    return v;
}
__device__ __forceinline__ float wsum16(float v) {
#pragma unroll
    for (int o = 8; o > 0; o >>= 1) v += __shfl_xor(v, o);
    return v;
}
__device__ __forceinline__ float4 wsum64_v4(float4 v) {
    v.x = wsum64(v.x); v.y = wsum64(v.y);
    v.z = wsum64(v.z); v.w = wsum64(v.w);
    return v;
}

// Protocol: msbuf[t*NWG + j] = bits of u_j(t) = sum_{c in band j} exp(l_c(t)).
// Max-free softmax is fp32-safe (logits O(0.3)). Sentinel 0xFFFFFFFF is never
// produced by exp-sums. All cross-WG traffic is relaxed agent-scope (sc1);
// the payload rides inside the 4B word itself, so no fences are needed.
__global__ __launch_bounds__(TPB, 1) void plastic_scan_kernel(
    const float* __restrict__ x,      // [BATCH][IN_F]
    const float* __restrict__ eta,    // [BATCH][IN_F][OUT_F]
    const float* __restrict__ w,      // [IN_F][OUT_F]
    const float* __restrict__ alpha,  // [IN_F][OUT_F]
    float* __restrict__ out,          // [BATCH][OUT_F]
    unsigned int* __restrict__ msbuf) // [BATCH][NWG], sentinel 0xFF
{
    // wred[wave][0..15]=A_c, [16..31]=B_c, [32]=maxBase,[33]=maxSlope+,[34]=minBase,[35]=minSlope-
    __shared__ __align__(16) float wred[4][40];
    __shared__ __align__(16) float wredL[4][16];  // honest-logit partials
    __shared__ __align__(16) float sXO[16];
    __shared__ float fAB[36];
    __shared__ unsigned int sFlag;

    const int tid = threadIdx.x;
    const int wv  = tid >> 6;
    const int pb  = blockIdx.x;
    const int j    = ((pb & 7) * (NWG / 8)) + (pb >> 3);  // XCD-banded remap
    const int col0 = j * BAND;
    const int r_[2] = { tid, tid + TPB };

    // ---- persistent per-thread state: 2 rows x 16 cols, all registers ----
    float4 w_[2][4], a_[2][4], tv_[2][4], ec_[2][4], en_[2][4];
#pragma unroll
    for (int r = 0; r < 2; ++r) {
        const float* wp = w + (size_t)r_[r] * OUT_F + col0;
        const float* ap = alpha + (size_t)r_[r] * OUT_F + col0;
#pragma unroll
        for (int k = 0; k < 4; ++k) {
            w_[r][k] = ld4(wp + 4 * k);
            a_[r][k] = ld4(ap + 4 * k);
            tv_[r][k] = make_float4(0.f, 0.f, 0.f, 0.f);
            en_[r][k] = make_float4(0.f, 0.f, 0.f, 0.f);
        }
    }
    const size_t estep = (size_t)IN_F * OUT_F;
    const float* ebase = eta + col0;
#pragma unroll
    for (int r = 0; r < 2; ++r) {
        const float* ep = ebase + (size_t)r_[r] * OUT_F;  // eta(0)
#pragma unroll
        for (int k = 0; k < 4; ++k) ec_[r][k] = ld4(ep + 4 * k);
    }
    float xP_[2], x1_[2], x2_[2];
#pragma unroll
    for (int r = 0; r < 2; ++r) {
        xP_[r] = x[r_[r]];
        x1_[r] = x[IN_F + r_[r]];
        x2_[r] = 0.f;
    }

    // ================= prologue =================
    // honest l(0) = x(0) @ w  (trace(0)=0)
    {
        float4 q_[4];
#pragma unroll
        for (int k = 0; k < 4; ++k) q_[k] = make_float4(0.f, 0.f, 0.f, 0.f);
#pragma unroll
        for (int r = 0; r < 2; ++r) {
            float xr = xP_[r];
#pragma unroll
            for (int k = 0; k < 4; ++k) {
                q_[k].x += xr * w_[r][k].x; q_[k].y += xr * w_[r][k].y;
                q_[k].z += xr * w_[r][k].z; q_[k].w += xr * w_[r][k].w;
            }
        }
#pragma unroll
        for (int k = 0; k < 4; ++k) q_[k] = wsum64_v4(q_[k]);
        if ((tid & 63) == 0) {
#pragma unroll
            for (int k = 0; k < 4; ++k) *(float4*)&wredL[wv][4 * k] = q_[k];
        }
    }
    // A/B/hull for publish target t=1: base=0, slope=eta(0)*x(0)
    {
        float4 pa_[4], pb_[4];
        float hsp = 0.f, hsn = 0.f;
#pragma unroll
        for (int k = 0; k < 4; ++k) {
            pa_[k] = make_float4(0.f, 0.f, 0.f, 0.f);
            pb_[k] = make_float4(0.f, 0.f, 0.f, 0.f);
        }
#pragma unroll
        for (int r = 0; r < 2; ++r) {
            float xpr = xP_[r], x1r = x1_[r];
#pragma unroll
            for (int k = 0; k < 4; ++k) {
                float4 e = ec_[r][k], w4 = w_[r][k], a4 = a_[r][k];
                float s0 = e.x * xpr, s1 = e.y * xpr, s2 = e.z * xpr, s3 = e.w * xpr;
                pa_[k].x += x1r * w4.x; pa_[k].y += x1r * w4.y;
                pa_[k].z += x1r * w4.z; pa_[k].w += x1r * w4.w;
                pb_[k].x += x1r * (a4.x * s0); pb_[k].y += x1r * (a4.y * s1);
                pb_[k].z += x1r * (a4.z * s2); pb_[k].w += x1r * (a4.w * s3);
                hsp = fmaxf(hsp, fmaxf(fmaxf(s0, s1), fmaxf(s2, s3)));
                hsn = fminf(hsn, fminf(fminf(s0, s1), fminf(s2, s3)));
            }
        }
#pragma unroll
        for (int k = 0; k < 4; ++k) { pa_[k] = wsum64_v4(pa_[k]); pb_[k] = wsum64_v4(pb_[k]); }
        hsp = wmax64(hsp); hsn = wmin64(hsn);
        if ((tid & 63) == 0) {
#pragma unroll
            for (int k = 0; k < 4; ++k) {
                *(float4*)&wred[wv][4 * k]      = pa_[k];
                *(float4*)&wred[wv][16 + 4 * k] = pb_[k];
            }
            wred[wv][32] = 0.f; wred[wv][33] = hsp;
            wred[wv][34] = 0.f; wred[wv][35] = hsn;
        }
    }
    __syncthreads();
    float e_cur = 0.f;  // lane c (<16): exp(l_c) of the step about to be consumed
    if (tid < 16) {
        float l = wredL[0][tid] + wredL[1][tid] + wredL[2][tid] + wredL[3][tid];
        e_cur = __expf(l);
        float u = wsum16(e_cur);
        if (tid == 0)
            __hip_atomic_store(&msbuf[j], __float_as_uint(u),
                               __ATOMIC_RELAXED, __HIP_MEMORY_SCOPE_AGENT);
    }

    // ================= steady loop =================
    for (int t = 0; t < BATCH; ++t) {
        // ---- top: issue hiding loads (consumed after the poll) ----
        if (t + 1 < BATCH) {
#pragma unroll
            for (int r = 0; r < 2; ++r) {
                const float* ep = ebase + (size_t)(t + 1) * estep + (size_t)r_[r] * OUT_F;
#pragma unroll
                for (int k = 0; k < 4; ++k) en_[r][k] = ld4(ep + 4 * k);
            }
        }
#pragma unroll
        for (int r = 0; r < 2; ++r)
            x2_[r] = (t + 2 < BATCH) ? x[(size_t)(t + 2) * IN_F + r_[r]] : 0.f;

        float fA = 0.f, fB = 0.f, h0 = 0.f, h1 = 0.f, h2 = 0.f, h3 = 0.f, S_tot = 0.f;
        if (tid < 64) {
            // parallel fold of wred -> fAB (lanes 0..35), then pick up operands
            float foldv = 0.f;
            if (tid < 32)
                foldv = wred[0][tid] + wred[1][tid] + wred[2][tid] + wred[3][tid];
            else if (tid < 34)
                foldv = fmaxf(fmaxf(wred[0][tid], wred[1][tid]),
                              fmaxf(wred[2][tid], wred[3][tid]));
            else if (tid < 36)
                foldv = fminf(fminf(wred[0][tid], wred[1][tid]),
                              fminf(wred[2][tid], wred[3][tid]));
            if (tid < 36) fAB[tid] = foldv;
            fA = foldv;                    // valid for lanes < 16 (A_c)
            fB = fAB[16 + (tid & 15)];
            h0 = fAB[32]; h1 = fAB[33]; h2 = fAB[34]; h3 = fAB[35];

            // ---- poll: 32 slots = one 128B line; all 64 lanes load (dup x2) ----
            const unsigned int* pa = msbuf + (size_t)t * NWG + (tid & 31);
            unsigned int v;
            for (;;) {
                asm volatile("global_load_dword %0, %1, off sc0 sc1\n\t"
                             "s_waitcnt vmcnt(0)"
                             : "=v"(v) : "v"(pa) : "memory");
                if (__all(v != SENT)) break;
            }
            float contrib = (tid < 32) ? __uint_as_float(v) : 0.f;
            S_tot = wsum64(contrib);
        }
        // ---- post-detect (lanes 0..15, lane c owns column c) ----
        if (tid < 16) {
            float rS = 1.0f / S_tot;
            float xo = e_cur * rS;
            out[(size_t)t * OUT_F + col0 + tid] = xo;
            sXO[tid] = xo;
            if (t < BATCH - 1) {
                float xom = xo;
#pragma unroll
                for (int o = 8; o > 0; o >>= 1) xom = fmaxf(xom, __shfl_xor(xom, o));
                bool ok = (h0 + h1 * xom <= 1.0f) && (h2 + h3 * xom >= -1.0f);
                if (ok) {
                    e_cur = __expf(fA + fB * xo);
                    float u = wsum16(e_cur);
                    if (tid == 0) {
                        __hip_atomic_store(&msbuf[(size_t)(t + 1) * NWG + j],
                                           __float_as_uint(u),
                                           __ATOMIC_RELAXED, __HIP_MEMORY_SCOPE_AGENT);
                        sFlag = 1u;
                    }
                } else if (tid == 0) {
                    sFlag = 0u;  // defer: honest publish after real trace update
                }
            }
        }
        __syncthreads();
        if (t == BATCH - 1) break;

        const unsigned int flag = sFlag;
        float4 xo4_[4];
#pragma unroll
        for (int k = 0; k < 4; ++k) xo4_[k] = *(const float4*)&sXO[4 * k];

        // ---- trace(t+1) = clip((1-eta(t))*tr + eta(t)*x(t)*xo(t)) ----
#pragma unroll
        for (int r = 0; r < 2; ++r) {
            float xr = xP_[r];
#pragma unroll
            for (int k = 0; k < 4; ++k) {
                float4 e = ec_[r][k];
                float4 tvv = tv_[r][k];
                tvv.x = clmp1((1.f - e.x) * tvv.x + e.x * (xr * xo4_[k].x));
                tvv.y = clmp1((1.f - e.y) * tvv.y + e.y * (xr * xo4_[k].y));
                tvv.z = clmp1((1.f - e.z) * tvv.z + e.z * (xr * xo4_[k].z));
                tvv.w = clmp1((1.f - e.w) * tvv.w + e.w * (xr * xo4_[k].w));
                tv_[r][k] = tvv;
            }
        }

        if (!flag) {
            // slow path (clip may fire): honest l(t+1) from clipped trace
            float4 q_[4];
#pragma unroll
            for (int k = 0; k < 4; ++k) q_[k] = make_float4(0.f, 0.f, 0.f, 0.f);
#pragma unroll
            for (int r = 0; r < 2; ++r) {
                float x1r = x1_[r];
#pragma unroll
                for (int k = 0; k < 4; ++k) {
                    float4 w4 = w_[r][k], a4 = a_[r][k], tvv = tv_[r][k];
                    q_[k].x += x1r * (w4.x + a4.x * tvv.x);
                    q_[k].y += x1r * (w4.y + a4.y * tvv.y);
                    q_[k].z += x1r * (w4.z + a4.z * tvv.z);
                    q_[k].w += x1r * (w4.w + a4.w * tvv.w);
                }
            }
#pragma unroll
            for (int k = 0; k < 4; ++k) q_[k] = wsum64_v4(q_[k]);
            if ((tid & 63) == 0) {
#pragma unroll
                for (int k = 0; k < 4; ++k) *(float4*)&wredL[wv][4 * k] = q_[k];
            }
            __syncthreads();
            if (tid < 16) {
                float l = wredL[0][tid] + wredL[1][tid] + wredL[2][tid] + wredL[3][tid];
                e_cur = __expf(l);
                float u = wsum16(e_cur);
                if (tid == 0)
                    __hip_atomic_store(&msbuf[(size_t)(t + 1) * NWG + j],
                                       __float_as_uint(u),
                                       __ATOMIC_RELAXED, __HIP_MEMORY_SCOPE_AGENT);
            }
        }

        // ---- shadow: A/B/hull for publish target t+2 ----
        if (t <= BATCH - 3) {
            float4 pa_[4], pb_[4];
            float hbp = -1e30f, hbn = 1e30f, hsp = 0.f, hsn = 0.f;
#pragma unroll
            for (int k = 0; k < 4; ++k) {
                pa_[k] = make_float4(0.f, 0.f, 0.f, 0.f);
                pb_[k] = make_float4(0.f, 0.f, 0.f, 0.f);
            }
#pragma unroll
            for (int r = 0; r < 2; ++r) {
                float x1r = x1_[r], x2r = x2_[r];
#pragma unroll
                for (int k = 0; k < 4; ++k) {
                    float4 e = en_[r][k], tvv = tv_[r][k], w4 = w_[r][k], a4 = a_[r][k];
                    float b0 = (1.f - e.x) * tvv.x, b1 = (1.f - e.y) * tvv.y;
                    float b2 = (1.f - e.z) * tvv.z, b3 = (1.f - e.w) * tvv.w;
                    float s0 = e.x * x1r, s1 = e.y * x1r, s2 = e.z * x1r, s3 = e.w * x1r;
                    pa_[k].x += x2r * (w4.x + a4.x * b0);
                    pa_[k].y += x2r * (w4.y + a4.y * b1);
                    pa_[k].z += x2r * (w4.z + a4.z * b2);
                    pa_[k].w += x2r * (w4.w + a4.w * b3);
                    pb_[k].x += x2r * (a4.x * s0);
                    pb_[k].y += x2r * (a4.y * s1);
                    pb_[k].z += x2r * (a4.z * s2);
                    pb_[k].w += x2r * (a4.w * s3);
                    hbp = fmaxf(hbp, fmaxf(fmaxf(b0, b1), fmaxf(b2, b3)));
                    hbn = fminf(hbn, fminf(fminf(b0, b1), fminf(b2, b3)));
                    hsp = fmaxf(hsp, fmaxf(fmaxf(s0, s1), fmaxf(s2, s3)));
                    hsn = fminf(hsn, fminf(fminf(s0, s1), fminf(s2, s3)));
                }
            }
#pragma unroll
            for (int k = 0; k < 4; ++k) { pa_[k] = wsum64_v4(pa_[k]); pb_[k] = wsum64_v4(pb_[k]); }
            hbp = wmax64(hbp); hsp = wmax64(hsp);
            hbn = wmin64(hbn); hsn = wmin64(hsn);
            if ((tid & 63) == 0) {
#pragma unroll
                for (int k = 0; k < 4; ++k) {
                    *(float4*)&wred[wv][4 * k]      = pa_[k];
                    *(float4*)&wred[wv][16 + 4 * k] = pb_[k];
                }
                wred[wv][32] = hbp; wred[wv][33] = hsp;
                wred[wv][34] = hbn; wred[wv][35] = hsn;
            }
        }

        // ---- rotate rings ----
#pragma unroll
        for (int r = 0; r < 2; ++r) {
            xP_[r] = x1_[r]; x1_[r] = x2_[r];
#pragma unroll
            for (int k = 0; k < 4; ++k) ec_[r][k] = en_[r][k];
        }
        __syncthreads();  // wred/sXO ready for next iteration
    }
}

extern "C" void kernel_launch(void* const* d_in, const int* in_sizes, int n_in,
                              void* d_out, int out_size, void* d_ws, size_t ws_size,
                              hipStream_t stream) {
    const float* x     = (const float*)d_in[0];
    const float* eta   = (const float*)d_in[1];
    const float* w     = (const float*)d_in[2];
    // d_in[3] = b: scalar added to all logits -> cancels in softmax, unused
    const float* alpha = (const float*)d_in[4];
    float* out = (float*)d_out;
    unsigned int* msbuf = (unsigned int*)d_ws;

    // sentinel-init the per-step exchange slots: 512*32*4B = 64 KiB
    hipMemsetAsync(d_ws, 0xFF, (size_t)BATCH * NWG * sizeof(unsigned int), stream);

    plastic_scan_kernel<<<dim3(NWG), dim3(TPB), 0, stream>>>(x, eta, w, alpha, out, msbuf);
}

// Round 5
// 1795.899 us; speedup vs baseline: 1.8089x; 1.8089x over previous
//
#include <hip/hip_runtime.h>
#include <stdint.h>

#define IN_F   512
#define OUT_F  512
#define BATCH  512
#define NWG    128
#define TPB    320   // wave 0 = comm-only (poll/publish); waves 1-4 = 256 data threads
#define BAND   4     // NWG*BAND == OUT_F

#define SENT 0xFFFFFFFFu

typedef unsigned int uint2v __attribute__((ext_vector_type(2)));

__device__ __forceinline__ float4 ld4(const float* p) {
    return *reinterpret_cast<const float4*>(p);
}
__device__ __forceinline__ float clmp1(float v) {
    return fminf(1.0f, fmaxf(-1.0f, v));
}
__device__ __forceinline__ float wsum(float v) {
#pragma unroll
    for (int o = 32; o > 0; o >>= 1) v += __shfl_xor(v, o);
    return v;
}
__device__ __forceinline__ float wmaxr(float v) {
#pragma unroll
    for (int o = 32; o > 0; o >>= 1) v = fmaxf(v, __shfl_xor(v, o));
    return v;
}
__device__ __forceinline__ float wminr(float v) {
#pragma unroll
    for (int o = 32; o > 0; o >>= 1) v = fminf(v, __shfl_xor(v, o));
    return v;
}

// Protocol: msbuf[t*NWG + j] = bits of u_j(t) = sum_{c in band j} exp(l_c(t)).
// Max-free softmax is fp32-safe (logits O(0.3)). Sentinel 0xFFFFFFFF never
// equals an exp-sum. Payload rides inside the 4B word -> relaxed agent scope,
// no fences. Wave 0 issues NO vmem except poll loads + publish store, so its
// vmcnt(0) is a clean coherence-point round trip (the R1-R4 kernels' polling
// wave also streamed eta; vmcnt(0) forced an HBM drain onto the scan chain).
__global__ __launch_bounds__(TPB, 1) void plastic_scan_kernel(
    const float* __restrict__ x,      // [BATCH][IN_F]
    const float* __restrict__ eta,    // [BATCH][IN_F][OUT_F]
    const float* __restrict__ w,      // [IN_F][OUT_F]
    const float* __restrict__ alpha,  // [IN_F][OUT_F]
    float* __restrict__ out,          // [BATCH][OUT_F]
    unsigned int* __restrict__ msbuf) // [BATCH][NWG], sentinel 0xFF
{
    // wred[dwave][0..3]=A_c, [4..7]=B_c, [8]=maxBase,[9]=maxSlope+,[10]=minBase,[11]=minSlope-
    __shared__ float wred[4][12];
    __shared__ float wredL[4][4];                 // honest-logit partials
    __shared__ __align__(16) float sXO[4];
    __shared__ unsigned int sFlag;

    const int tid = threadIdx.x;
    const int pb  = blockIdx.x;
    const int j    = ((pb & 7) * (NWG / 8)) + (pb >> 3);  // XCD-banded remap
    const int col0 = j * BAND;
    const bool isData = (tid >= 64);
    const int dt = tid - 64;          // 0..255 for data threads
    const int wi = (tid >> 6) - 1;    // data wave index 0..3
    const int r0 = dt;
    const int r1 = dt + 256;

    const size_t estep = (size_t)IN_F * OUT_F;
    const float* ebase = eta + col0;

    // ---- data-thread persistent state (registers) ----
    float4 wA, wB, aA, aB, trA, trB;
    float4 e0A, e0B, e1A, e1B, e2A, e2B;          // eta(t), eta(t+1), eta(t+2)
    float xPA = 0, xPB = 0, x1A = 0, x1B = 0, x2A = 0, x2B = 0;
    if (isData) {
        wA = ld4(&w[(size_t)r0 * OUT_F + col0]);
        wB = ld4(&w[(size_t)r1 * OUT_F + col0]);
        aA = ld4(&alpha[(size_t)r0 * OUT_F + col0]);
        aB = ld4(&alpha[(size_t)r1 * OUT_F + col0]);
        trA = make_float4(0.f, 0.f, 0.f, 0.f);
        trB = make_float4(0.f, 0.f, 0.f, 0.f);
        e0A = ld4(ebase + 0 * estep + (size_t)r0 * OUT_F);
        e0B = ld4(ebase + 0 * estep + (size_t)r1 * OUT_F);
        e1A = ld4(ebase + 1 * estep + (size_t)r0 * OUT_F);
        e1B = ld4(ebase + 1 * estep + (size_t)r1 * OUT_F);
        e2A = ld4(ebase + 2 * estep + (size_t)r0 * OUT_F);
        e2B = ld4(ebase + 2 * estep + (size_t)r1 * OUT_F);
        xPA = x[r0];            xPB = x[r1];
        x1A = x[IN_F + r0];     x1B = x[IN_F + r1];
        x2A = x[2 * IN_F + r0]; x2B = x[2 * IN_F + r1];
    }

    // ---- comm-wave lane-0 persistent state ----
    float e0 = 0, e1 = 0, e2 = 0, e3 = 0;  // exp(l_c) of step about to be consumed
    float A0, A1, A2, A3, B0, B1, B2, B3, hBp, hSp, hBn, hSn;

    // ================= prologue (data waves) =================
    if (isData) {
        // honest l(0) = x(0) @ w  (trace(0)=0)
        float p0 = xPA * wA.x + xPB * wB.x;
        float p1 = xPA * wA.y + xPB * wB.y;
        float p2 = xPA * wA.z + xPB * wB.z;
        float p3 = xPA * wA.w + xPB * wB.w;
        p0 = wsum(p0); p1 = wsum(p1); p2 = wsum(p2); p3 = wsum(p3);
        if ((tid & 63) == 0) {
            wredL[wi][0] = p0; wredL[wi][1] = p1;
            wredL[wi][2] = p2; wredL[wi][3] = p3;
        }
        // A/B/hull for publish target t=1: base=0, slope=eta(0)*x(0)
        float sA0 = e0A.x * xPA, sA1 = e0A.y * xPA, sA2 = e0A.z * xPA, sA3 = e0A.w * xPA;
        float sB0 = e0B.x * xPB, sB1 = e0B.y * xPB, sB2 = e0B.z * xPB, sB3 = e0B.w * xPB;
        float pA0 = x1A * wA.x + x1B * wB.x;
        float pA1 = x1A * wA.y + x1B * wB.y;
        float pA2 = x1A * wA.z + x1B * wB.z;
        float pA3 = x1A * wA.w + x1B * wB.w;
        float pB0 = x1A * (aA.x * sA0) + x1B * (aB.x * sB0);
        float pB1 = x1A * (aA.y * sA1) + x1B * (aB.y * sB1);
        float pB2 = x1A * (aA.z * sA2) + x1B * (aB.z * sB2);
        float pB3 = x1A * (aA.w * sA3) + x1B * (aB.w * sB3);
        float hsp = fmaxf(fmaxf(fmaxf(sA0, sA1), fmaxf(sA2, sA3)),
                          fmaxf(fmaxf(sB0, sB1), fmaxf(sB2, sB3)));
        hsp = fmaxf(hsp, 0.f);
        float hsn = fminf(fminf(fminf(sA0, sA1), fminf(sA2, sA3)),
                          fminf(fminf(sB0, sB1), fminf(sB2, sB3)));
        hsn = fminf(hsn, 0.f);
        pA0 = wsum(pA0); pA1 = wsum(pA1); pA2 = wsum(pA2); pA3 = wsum(pA3);
        pB0 = wsum(pB0); pB1 = wsum(pB1); pB2 = wsum(pB2); pB3 = wsum(pB3);
        hsp = wmaxr(hsp); hsn = wminr(hsn);
        if ((tid & 63) == 0) {
            float* wr = wred[wi];
            wr[0] = pA0; wr[1] = pA1; wr[2] = pA2; wr[3] = pA3;
            wr[4] = pB0; wr[5] = pB1; wr[6] = pB2; wr[7] = pB3;
            wr[8] = 0.f; wr[9] = hsp; wr[10] = 0.f; wr[11] = hsn;
        }
    }
    __syncthreads();
    if (tid == 0) {
        float l0 = wredL[0][0] + wredL[1][0] + wredL[2][0] + wredL[3][0];
        float l1 = wredL[0][1] + wredL[1][1] + wredL[2][1] + wredL[3][1];
        float l2 = wredL[0][2] + wredL[1][2] + wredL[2][2] + wredL[3][2];
        float l3 = wredL[0][3] + wredL[1][3] + wredL[2][3] + wredL[3][3];
        e0 = __expf(l0); e1 = __expf(l1); e2 = __expf(l2); e3 = __expf(l3);
        float u = (e0 + e1) + (e2 + e3);
        __hip_atomic_store(&msbuf[j], __float_as_uint(u),
                           __ATOMIC_RELAXED, __HIP_MEMORY_SCOPE_AGENT);
    }

    // ================= steady loop =================
    for (int t = 0; t < BATCH; ++t) {
        float4 e3A, e3B;
        if (isData) {
            // issue eta(t+3): >=2 full steps of lead before consumption
            if (t + 3 < BATCH) {
                e3A = ld4(ebase + (size_t)(t + 3) * estep + (size_t)r0 * OUT_F);
                e3B = ld4(ebase + (size_t)(t + 3) * estep + (size_t)r1 * OUT_F);
            } else {
                e3A = make_float4(0.f, 0.f, 0.f, 0.f);
                e3B = make_float4(0.f, 0.f, 0.f, 0.f);
            }
        }
        float S_tot = 0.f;
        if (tid < 64) {
            // lane0: fold shadow A/B/hull (pre-poll, off the detect->publish path)
            if (tid == 0) {
                A0 = wred[0][0] + wred[1][0] + wred[2][0] + wred[3][0];
                A1 = wred[0][1] + wred[1][1] + wred[2][1] + wred[3][1];
                A2 = wred[0][2] + wred[1][2] + wred[2][2] + wred[3][2];
                A3 = wred[0][3] + wred[1][3] + wred[2][3] + wred[3][3];
                B0 = wred[0][4] + wred[1][4] + wred[2][4] + wred[3][4];
                B1 = wred[0][5] + wred[1][5] + wred[2][5] + wred[3][5];
                B2 = wred[0][6] + wred[1][6] + wred[2][6] + wred[3][6];
                B3 = wred[0][7] + wred[1][7] + wred[2][7] + wred[3][7];
                hBp = fmaxf(fmaxf(wred[0][8], wred[1][8]), fmaxf(wred[2][8], wred[3][8]));
                hSp = fmaxf(fmaxf(wred[0][9], wred[1][9]), fmaxf(wred[2][9], wred[3][9]));
                hBn = fminf(fminf(wred[0][10], wred[1][10]), fminf(wred[2][10], wred[3][10]));
                hSn = fminf(fminf(wred[0][11], wred[1][11]), fminf(wred[2][11], wred[3][11]));
            }
            // poll all 128 u_j(t): one dwordx2 per lane; this wave has no other
            // outstanding vmem, so vmcnt(0) = clean coherence-point RT
            const unsigned int* pa = msbuf + (size_t)t * NWG + 2 * tid;
            uint2v v;
            for (;;) {
                asm volatile("global_load_dwordx2 %0, %1, off sc0 sc1\n\t"
                             "s_waitcnt vmcnt(0)"
                             : "=v"(v) : "v"(pa) : "memory");
                if (__all((v.x != SENT) & (v.y != SENT))) break;
            }
            S_tot = wsum(__uint_as_float(v.x) + __uint_as_float(v.y));
        }
        // lane0: softmax of own band + immediate linearized publish
        if (tid == 0) {
            float rS = 1.0f / S_tot;
            float xo0 = e0 * rS, xo1 = e1 * rS, xo2 = e2 * rS, xo3 = e3 * rS;
            unsigned int flag = 1u;
            if (t < BATCH - 1) {
                float xom = fmaxf(fmaxf(xo0, xo1), fmaxf(xo2, xo3));
                bool ok = (hBp + hSp * xom <= 1.0f) && (hBn + hSn * xom >= -1.0f);
                if (ok) {
                    e0 = __expf(A0 + B0 * xo0); e1 = __expf(A1 + B1 * xo1);
                    e2 = __expf(A2 + B2 * xo2); e3 = __expf(A3 + B3 * xo3);
                    float u = (e0 + e1) + (e2 + e3);
                    __hip_atomic_store(&msbuf[(size_t)(t + 1) * NWG + j],
                                       __float_as_uint(u),
                                       __ATOMIC_RELAXED, __HIP_MEMORY_SCOPE_AGENT);
                } else {
                    flag = 0u;  // defer: honest publish after real trace update
                }
            }
            sXO[0] = xo0; sXO[1] = xo1; sXO[2] = xo2; sXO[3] = xo3;
            sFlag = flag;
        }
        __syncthreads();
        // out store by a data thread (keeps comm wave's vmcnt clean)
        if (tid == 64) {
            *(float4*)&out[(size_t)t * OUT_F + col0] = *(const float4*)&sXO[0];
        }
        if (t == BATCH - 1) break;

        const unsigned int flag = sFlag;
        const float xo0 = sXO[0], xo1 = sXO[1], xo2 = sXO[2], xo3 = sXO[3];

        if (isData) {
            // trace(t+1) = clip((1-eta(t))*tr + eta(t)*x(t)*xo(t))
            trA.x = clmp1((1.f - e0A.x) * trA.x + e0A.x * (xPA * xo0));
            trA.y = clmp1((1.f - e0A.y) * trA.y + e0A.y * (xPA * xo1));
            trA.z = clmp1((1.f - e0A.z) * trA.z + e0A.z * (xPA * xo2));
            trA.w = clmp1((1.f - e0A.w) * trA.w + e0A.w * (xPA * xo3));
            trB.x = clmp1((1.f - e0B.x) * trB.x + e0B.x * (xPB * xo0));
            trB.y = clmp1((1.f - e0B.y) * trB.y + e0B.y * (xPB * xo1));
            trB.z = clmp1((1.f - e0B.z) * trB.z + e0B.z * (xPB * xo2));
            trB.w = clmp1((1.f - e0B.w) * trB.w + e0B.w * (xPB * xo3));
        }

        if (!flag) {  // uniform branch (sFlag broadcast) — rare/never
            if (isData) {
                float p0 = x1A * (wA.x + aA.x * trA.x) + x1B * (wB.x + aB.x * trB.x);
                float p1 = x1A * (wA.y + aA.y * trA.y) + x1B * (wB.y + aB.y * trB.y);
                float p2 = x1A * (wA.z + aA.z * trA.z) + x1B * (wB.z + aB.z * trB.z);
                float p3 = x1A * (wA.w + aA.w * trA.w) + x1B * (wB.w + aB.w * trB.w);
                p0 = wsum(p0); p1 = wsum(p1); p2 = wsum(p2); p3 = wsum(p3);
                if ((tid & 63) == 0) {
                    wredL[wi][0] = p0; wredL[wi][1] = p1;
                    wredL[wi][2] = p2; wredL[wi][3] = p3;
                }
            }
            __syncthreads();
            if (tid == 0) {
                float l0 = wredL[0][0] + wredL[1][0] + wredL[2][0] + wredL[3][0];
                float l1 = wredL[0][1] + wredL[1][1] + wredL[2][1] + wredL[3][1];
                float l2 = wredL[0][2] + wredL[1][2] + wredL[2][2] + wredL[3][2];
                float l3 = wredL[0][3] + wredL[1][3] + wredL[2][3] + wredL[3][3];
                e0 = __expf(l0); e1 = __expf(l1); e2 = __expf(l2); e3 = __expf(l3);
                float u = (e0 + e1) + (e2 + e3);
                __hip_atomic_store(&msbuf[(size_t)(t + 1) * NWG + j],
                                   __float_as_uint(u),
                                   __ATOMIC_RELAXED, __HIP_MEMORY_SCOPE_AGENT);
            }
        }

        if (isData) {
            // shadow: A/B/hull for publish target t+2
            if (t <= BATCH - 3) {
                float bA0 = (1.f - e1A.x) * trA.x, bA1 = (1.f - e1A.y) * trA.y;
                float bA2 = (1.f - e1A.z) * trA.z, bA3 = (1.f - e1A.w) * trA.w;
                float bB0 = (1.f - e1B.x) * trB.x, bB1 = (1.f - e1B.y) * trB.y;
                float bB2 = (1.f - e1B.z) * trB.z, bB3 = (1.f - e1B.w) * trB.w;
                float sA0 = e1A.x * x1A, sA1 = e1A.y * x1A, sA2 = e1A.z * x1A, sA3 = e1A.w * x1A;
                float sB0 = e1B.x * x1B, sB1 = e1B.y * x1B, sB2 = e1B.z * x1B, sB3 = e1B.w * x1B;
                float pA0 = x2A * (wA.x + aA.x * bA0) + x2B * (wB.x + aB.x * bB0);
                float pA1 = x2A * (wA.y + aA.y * bA1) + x2B * (wB.y + aB.y * bB1);
                float pA2 = x2A * (wA.z + aA.z * bA2) + x2B * (wB.z + aB.z * bB2);
                float pA3 = x2A * (wA.w + aA.w * bA3) + x2B * (wB.w + aB.w * bB3);
                float pB0 = x2A * (aA.x * sA0) + x2B * (aB.x * sB0);
                float pB1 = x2A * (aA.y * sA1) + x2B * (aB.y * sB1);
                float pB2 = x2A * (aA.z * sA2) + x2B * (aB.z * sB2);
                float pB3 = x2A * (aA.w * sA3) + x2B * (aB.w * sB3);
                float hbp = fmaxf(fmaxf(fmaxf(bA0, bA1), fmaxf(bA2, bA3)),
                                  fmaxf(fmaxf(bB0, bB1), fmaxf(bB2, bB3)));
                float hbn = fminf(fminf(fminf(bA0, bA1), fminf(bA2, bA3)),
                                  fminf(fminf(bB0, bB1), fminf(bB2, bB3)));
                float hsp = fmaxf(fmaxf(fmaxf(sA0, sA1), fmaxf(sA2, sA3)),
                                  fmaxf(fmaxf(sB0, sB1), fmaxf(sB2, sB3)));
                hsp = fmaxf(hsp, 0.f);
                float hsn = fminf(fminf(fminf(sA0, sA1), fminf(sA2, sA3)),
                                  fminf(fminf(sB0, sB1), fminf(sB2, sB3)));
                hsn = fminf(hsn, 0.f);
                pA0 = wsum(pA0); pA1 = wsum(pA1); pA2 = wsum(pA2); pA3 = wsum(pA3);
                pB0 = wsum(pB0); pB1 = wsum(pB1); pB2 = wsum(pB2); pB3 = wsum(pB3);
                hbp = wmaxr(hbp); hsp = wmaxr(hsp);
                hbn = wminr(hbn); hsn = wminr(hsn);
                if ((tid & 63) == 0) {
                    float* wr = wred[wi];
                    wr[0] = pA0; wr[1] = pA1; wr[2] = pA2; wr[3] = pA3;
                    wr[4] = pB0; wr[5] = pB1; wr[6] = pB2; wr[7] = pB3;
                    wr[8] = hbp; wr[9] = hsp; wr[10] = hbn; wr[11] = hsn;
                }
            }
            // rotate rings
            e0A = e1A; e0B = e1B; e1A = e2A; e1B = e2B; e2A = e3A; e2B = e3B;
            xPA = x1A; xPB = x1B; x1A = x2A; x1B = x2B;
            if (t + 3 < BATCH) {
                x2A = x[(size_t)(t + 3) * IN_F + r0];
                x2B = x[(size_t)(t + 3) * IN_F + r1];
            }
        }
        __syncthreads();  // wred ready for next iteration's fold
    }
}

extern "C" void kernel_launch(void* const* d_in, const int* in_sizes, int n_in,
                              void* d_out, int out_size, void* d_ws, size_t ws_size,
                              hipStream_t stream) {
    const float* x     = (const float*)d_in[0];
    const float* eta   = (const float*)d_in[1];
    const float* w     = (const float*)d_in[2];
    // d_in[3] = b: scalar added to all logits -> cancels in softmax, unused
    const float* alpha = (const float*)d_in[4];
    float* out = (float*)d_out;
    unsigned int* msbuf = (unsigned int*)d_ws;

    // sentinel-init the per-step exchange slots: 512*128*4B = 256 KiB
    hipMemsetAsync(d_ws, 0xFF, (size_t)BATCH * NWG * sizeof(unsigned int), stream);

    plastic_scan_kernel<<<dim3(NWG), dim3(TPB), 0, stream>>>(x, eta, w, alpha, out, msbuf);
}

// Round 6
// 1469.092 us; speedup vs baseline: 2.2113x; 1.2225x over previous
//
#include <hip/hip_runtime.h>
#include <stdint.h>

#define IN_F   512
#define OUT_F  512
#define BATCH  512
#define NWG    128
#define TPB    320   // wave 0 = comm-only; waves 1-4 = 256 data threads
#define BAND   4     // NWG*BAND == OUT_F

#define SENT 0xFFFFFFFFu

typedef unsigned int uint2v __attribute__((ext_vector_type(2)));

__device__ __forceinline__ float4 ld4(const float* p) {
    return *reinterpret_cast<const float4*>(p);
}
__device__ __forceinline__ float clmp1(float v) {
    return fminf(1.0f, fmaxf(-1.0f, v));
}
__device__ __forceinline__ float wsum(float v) {
#pragma unroll
    for (int o = 32; o > 0; o >>= 1) v += __shfl_xor(v, o);
    return v;
}
__device__ __forceinline__ float wmaxr(float v) {
#pragma unroll
    for (int o = 32; o > 0; o >>= 1) v = fmaxf(v, __shfl_xor(v, o));
    return v;
}
__device__ __forceinline__ float wminr(float v) {
#pragma unroll
    for (int o = 32; o > 0; o >>= 1) v = fminf(v, __shfl_xor(v, o));
    return v;
}

// Star-topology exchange:
//   publishers: msbuf[t*NWG + j] = u_j(t) = sum_c exp(l_c(t))   (128 writers, ONE reader)
//   aggregator (WG 0, wave 0): polls all 128, S(t) = sum_j u_j(t),
//     broadcasts S(t) to 128 PRIVATE line-disjoint slots bcast[t][j] (stride 1<<bshift dwords)
//   all other WGs: poll ONLY their own bcast line (64 lanes, same addr -> 1 request)
// No cache line is ever polled by more than one WG -> no same-line read
// serialization at the coherence point. Max-free softmax is fp32-safe
// (logits O(0.3)); sentinel 0xFFFFFFFF never equals an exp-sum. Payload rides
// inside the 4B word -> relaxed agent scope, no fences needed.
__global__ __launch_bounds__(TPB, 1) void plastic_scan_kernel(
    const float* __restrict__ x,      // [BATCH][IN_F]
    const float* __restrict__ eta,    // [BATCH][IN_F][OUT_F]
    const float* __restrict__ w,      // [IN_F][OUT_F]
    const float* __restrict__ alpha,  // [IN_F][OUT_F]
    float* __restrict__ out,          // [BATCH][OUT_F]
    unsigned int* __restrict__ msbuf, // [BATCH][NWG] publish slots, sentinel 0xFF
    unsigned int* __restrict__ bcast, // [BATCH][NWG<<bshift] private S slots, sentinel 0xFF
    int bshift)
{
    __shared__ float wred[4][12];   // [dwave][0..3]=A, [4..7]=B, [8..11]=hull
    __shared__ float wredL[4][4];   // honest-logit partials
    __shared__ __align__(16) float sXO[4];
    __shared__ unsigned int sFlag;

    const int tid = threadIdx.x;
    const int pb  = blockIdx.x;
    const int j    = ((pb & 7) * (NWG / 8)) + (pb >> 3);  // XCD-banded remap
    const int col0 = j * BAND;
    const bool isData = (tid >= 64);
    const int dt = tid - 64;
    const int wi = (tid >> 6) - 1;
    const int r0 = dt;
    const int r1 = dt + 256;

    const size_t estep = (size_t)IN_F * OUT_F;
    const float* ebase = eta + col0;

    // ---- data-thread persistent state (registers) ----
    float4 wA, wB, aA, aB, trA, trB;
    float4 e0A, e0B, e1A, e1B, e2A, e2B;
    float xPA = 0, xPB = 0, x1A = 0, x1B = 0, x2A = 0, x2B = 0;
    if (isData) {
        wA = ld4(&w[(size_t)r0 * OUT_F + col0]);
        wB = ld4(&w[(size_t)r1 * OUT_F + col0]);
        aA = ld4(&alpha[(size_t)r0 * OUT_F + col0]);
        aB = ld4(&alpha[(size_t)r1 * OUT_F + col0]);
        trA = make_float4(0.f, 0.f, 0.f, 0.f);
        trB = make_float4(0.f, 0.f, 0.f, 0.f);
        e0A = ld4(ebase + 0 * estep + (size_t)r0 * OUT_F);
        e0B = ld4(ebase + 0 * estep + (size_t)r1 * OUT_F);
        e1A = ld4(ebase + 1 * estep + (size_t)r0 * OUT_F);
        e1B = ld4(ebase + 1 * estep + (size_t)r1 * OUT_F);
        e2A = ld4(ebase + 2 * estep + (size_t)r0 * OUT_F);
        e2B = ld4(ebase + 2 * estep + (size_t)r1 * OUT_F);
        xPA = x[r0];            xPB = x[r1];
        x1A = x[IN_F + r0];     x1B = x[IN_F + r1];
        x2A = x[2 * IN_F + r0]; x2B = x[2 * IN_F + r1];
    }

    // ---- comm-wave lane-0 persistent state ----
    float e0 = 0, e1 = 0, e2 = 0, e3 = 0;
    float A0, A1, A2, A3, B0, B1, B2, B3, hBp, hSp, hBn, hSn;

    // ================= prologue (data waves) =================
    if (isData) {
        // honest l(0) = x(0) @ w  (trace(0)=0)
        float p0 = xPA * wA.x + xPB * wB.x;
        float p1 = xPA * wA.y + xPB * wB.y;
        float p2 = xPA * wA.z + xPB * wB.z;
        float p3 = xPA * wA.w + xPB * wB.w;
        p0 = wsum(p0); p1 = wsum(p1); p2 = wsum(p2); p3 = wsum(p3);
        if ((tid & 63) == 0) {
            wredL[wi][0] = p0; wredL[wi][1] = p1;
            wredL[wi][2] = p2; wredL[wi][3] = p3;
        }
        // A/B/hull for publish target t=1: base=0, slope=eta(0)*x(0)
        float sA0 = e0A.x * xPA, sA1 = e0A.y * xPA, sA2 = e0A.z * xPA, sA3 = e0A.w * xPA;
        float sB0 = e0B.x * xPB, sB1 = e0B.y * xPB, sB2 = e0B.z * xPB, sB3 = e0B.w * xPB;
        float pA0 = x1A * wA.x + x1B * wB.x;
        float pA1 = x1A * wA.y + x1B * wB.y;
        float pA2 = x1A * wA.z + x1B * wB.z;
        float pA3 = x1A * wA.w + x1B * wB.w;
        float pB0 = x1A * (aA.x * sA0) + x1B * (aB.x * sB0);
        float pB1 = x1A * (aA.y * sA1) + x1B * (aB.y * sB1);
        float pB2 = x1A * (aA.z * sA2) + x1B * (aB.z * sB2);
        float pB3 = x1A * (aA.w * sA3) + x1B * (aB.w * sB3);
        float hsp = fmaxf(fmaxf(fmaxf(sA0, sA1), fmaxf(sA2, sA3)),
                          fmaxf(fmaxf(sB0, sB1), fmaxf(sB2, sB3)));
        hsp = fmaxf(hsp, 0.f);
        float hsn = fminf(fminf(fminf(sA0, sA1), fminf(sA2, sA3)),
                          fminf(fminf(sB0, sB1), fminf(sB2, sB3)));
        hsn = fminf(hsn, 0.f);
        pA0 = wsum(pA0); pA1 = wsum(pA1); pA2 = wsum(pA2); pA3 = wsum(pA3);
        pB0 = wsum(pB0); pB1 = wsum(pB1); pB2 = wsum(pB2); pB3 = wsum(pB3);
        hsp = wmaxr(hsp); hsn = wminr(hsn);
        if ((tid & 63) == 0) {
            float* wr = wred[wi];
            wr[0] = pA0; wr[1] = pA1; wr[2] = pA2; wr[3] = pA3;
            wr[4] = pB0; wr[5] = pB1; wr[6] = pB2; wr[7] = pB3;
            wr[8] = 0.f; wr[9] = hsp; wr[10] = 0.f; wr[11] = hsn;
        }
    }
    __syncthreads();
    if (tid == 0) {
        float l0 = wredL[0][0] + wredL[1][0] + wredL[2][0] + wredL[3][0];
        float l1 = wredL[0][1] + wredL[1][1] + wredL[2][1] + wredL[3][1];
        float l2 = wredL[0][2] + wredL[1][2] + wredL[2][2] + wredL[3][2];
        float l3 = wredL[0][3] + wredL[1][3] + wredL[2][3] + wredL[3][3];
        e0 = __expf(l0); e1 = __expf(l1); e2 = __expf(l2); e3 = __expf(l3);
        float u = (e0 + e1) + (e2 + e3);
        __hip_atomic_store(&msbuf[j], __float_as_uint(u),
                           __ATOMIC_RELAXED, __HIP_MEMORY_SCOPE_AGENT);
    }

    // ================= steady loop =================
    for (int t = 0; t < BATCH; ++t) {
        float4 e3A, e3B;
        if (isData) {
            if (t + 3 < BATCH) {
                e3A = ld4(ebase + (size_t)(t + 3) * estep + (size_t)r0 * OUT_F);
                e3B = ld4(ebase + (size_t)(t + 3) * estep + (size_t)r1 * OUT_F);
            } else {
                e3A = make_float4(0.f, 0.f, 0.f, 0.f);
                e3B = make_float4(0.f, 0.f, 0.f, 0.f);
            }
        }
        float S_tot = 0.f;
        if (tid < 64) {
            // lane0: fold shadow A/B/hull (pre-poll, off the critical path)
            if (tid == 0) {
                A0 = wred[0][0] + wred[1][0] + wred[2][0] + wred[3][0];
                A1 = wred[0][1] + wred[1][1] + wred[2][1] + wred[3][1];
                A2 = wred[0][2] + wred[1][2] + wred[2][2] + wred[3][2];
                A3 = wred[0][3] + wred[1][3] + wred[2][3] + wred[3][3];
                B0 = wred[0][4] + wred[1][4] + wred[2][4] + wred[3][4];
                B1 = wred[0][5] + wred[1][5] + wred[2][5] + wred[3][5];
                B2 = wred[0][6] + wred[1][6] + wred[2][6] + wred[3][6];
                B3 = wred[0][7] + wred[1][7] + wred[2][7] + wred[3][7];
                hBp = fmaxf(fmaxf(wred[0][8], wred[1][8]), fmaxf(wred[2][8], wred[3][8]));
                hSp = fmaxf(fmaxf(wred[0][9], wred[1][9]), fmaxf(wred[2][9], wred[3][9]));
                hBn = fminf(fminf(wred[0][10], wred[1][10]), fminf(wred[2][10], wred[3][10]));
                hSn = fminf(fminf(wred[0][11], wred[1][11]), fminf(wred[2][11], wred[3][11]));
            }
            if (pb == 0) {
                // ---- aggregator: sole reader of the 128 publish slots ----
                const unsigned int* pa = msbuf + (size_t)t * NWG + 2 * tid;
                uint2v v;
                for (;;) {
                    asm volatile("global_load_dwordx2 %0, %1, off sc0 sc1\n\t"
                                 "s_waitcnt vmcnt(0)"
                                 : "=v"(v) : "v"(pa) : "memory");
                    if (__all((v.x != SENT) & (v.y != SENT))) break;
                }
                S_tot = wsum(__uint_as_float(v.x) + __uint_as_float(v.y));
                // broadcast S to 128 private line-disjoint slots (2 stores/lane)
                unsigned int sbits = __float_as_uint(S_tot);
                unsigned int* pb0 = bcast + (((size_t)t * NWG) << bshift)
                                          + (((size_t)(2 * tid)) << bshift);
                unsigned int* pb1 = pb0 + ((size_t)1 << bshift);
                __hip_atomic_store(pb0, sbits, __ATOMIC_RELAXED, __HIP_MEMORY_SCOPE_AGENT);
                __hip_atomic_store(pb1, sbits, __ATOMIC_RELAXED, __HIP_MEMORY_SCOPE_AGENT);
            } else {
                // ---- poll ONLY this WG's private line (no sharing) ----
                const unsigned int* pq = bcast + (((size_t)t * NWG) << bshift)
                                               + (((size_t)j) << bshift);
                unsigned int v;
                for (;;) {
                    asm volatile("global_load_dword %0, %1, off sc0 sc1\n\t"
                                 "s_waitcnt vmcnt(0)"
                                 : "=v"(v) : "v"(pq) : "memory");
                    if (v != SENT) break;
                }
                S_tot = __uint_as_float(v);
            }
        }
        // lane0: softmax of own band + immediate linearized publish
        if (tid == 0) {
            float rS = 1.0f / S_tot;
            float xo0 = e0 * rS, xo1 = e1 * rS, xo2 = e2 * rS, xo3 = e3 * rS;
            unsigned int flag = 1u;
            if (t < BATCH - 1) {
                float xom = fmaxf(fmaxf(xo0, xo1), fmaxf(xo2, xo3));
                bool ok = (hBp + hSp * xom <= 1.0f) && (hBn + hSn * xom >= -1.0f);
                if (ok) {
                    e0 = __expf(A0 + B0 * xo0); e1 = __expf(A1 + B1 * xo1);
                    e2 = __expf(A2 + B2 * xo2); e3 = __expf(A3 + B3 * xo3);
                    float u = (e0 + e1) + (e2 + e3);
                    __hip_atomic_store(&msbuf[(size_t)(t + 1) * NWG + j],
                                       __float_as_uint(u),
                                       __ATOMIC_RELAXED, __HIP_MEMORY_SCOPE_AGENT);
                } else {
                    flag = 0u;  // defer: honest publish after real trace update
                }
            }
            sXO[0] = xo0; sXO[1] = xo1; sXO[2] = xo2; sXO[3] = xo3;
            sFlag = flag;
        }
        __syncthreads();
        if (tid == 64) {
            *(float4*)&out[(size_t)t * OUT_F + col0] = *(const float4*)&sXO[0];
        }
        if (t == BATCH - 1) break;

        const unsigned int flag = sFlag;
        const float xo0 = sXO[0], xo1 = sXO[1], xo2 = sXO[2], xo3 = sXO[3];

        if (isData) {
            trA.x = clmp1((1.f - e0A.x) * trA.x + e0A.x * (xPA * xo0));
            trA.y = clmp1((1.f - e0A.y) * trA.y + e0A.y * (xPA * xo1));
            trA.z = clmp1((1.f - e0A.z) * trA.z + e0A.z * (xPA * xo2));
            trA.w = clmp1((1.f - e0A.w) * trA.w + e0A.w * (xPA * xo3));
            trB.x = clmp1((1.f - e0B.x) * trB.x + e0B.x * (xPB * xo0));
            trB.y = clmp1((1.f - e0B.y) * trB.y + e0B.y * (xPB * xo1));
            trB.z = clmp1((1.f - e0B.z) * trB.z + e0B.z * (xPB * xo2));
            trB.w = clmp1((1.f - e0B.w) * trB.w + e0B.w * (xPB * xo3));
        }

        if (!flag) {  // uniform branch — rare/never
            if (isData) {
                float p0 = x1A * (wA.x + aA.x * trA.x) + x1B * (wB.x + aB.x * trB.x);
                float p1 = x1A * (wA.y + aA.y * trA.y) + x1B * (wB.y + aB.y * trB.y);
                float p2 = x1A * (wA.z + aA.z * trA.z) + x1B * (wB.z + aB.z * trB.z);
                float p3 = x1A * (wA.w + aA.w * trA.w) + x1B * (wB.w + aB.w * trB.w);
                p0 = wsum(p0); p1 = wsum(p1); p2 = wsum(p2); p3 = wsum(p3);
                if ((tid & 63) == 0) {
                    wredL[wi][0] = p0; wredL[wi][1] = p1;
                    wredL[wi][2] = p2; wredL[wi][3] = p3;
                }
            }
            __syncthreads();
            if (tid == 0) {
                float l0 = wredL[0][0] + wredL[1][0] + wredL[2][0] + wredL[3][0];
                float l1 = wredL[0][1] + wredL[1][1] + wredL[2][1] + wredL[3][1];
                float l2 = wredL[0][2] + wredL[1][2] + wredL[2][2] + wredL[3][2];
                float l3 = wredL[0][3] + wredL[1][3] + wredL[2][3] + wredL[3][3];
                e0 = __expf(l0); e1 = __expf(l1); e2 = __expf(l2); e3 = __expf(l3);
                float u = (e0 + e1) + (e2 + e3);
                __hip_atomic_store(&msbuf[(size_t)(t + 1) * NWG + j],
                                   __float_as_uint(u),
                                   __ATOMIC_RELAXED, __HIP_MEMORY_SCOPE_AGENT);
            }
        }

        if (isData) {
            // shadow: A/B/hull for publish target t+2
            if (t <= BATCH - 3) {
                float bA0 = (1.f - e1A.x) * trA.x, bA1 = (1.f - e1A.y) * trA.y;
                float bA2 = (1.f - e1A.z) * trA.z, bA3 = (1.f - e1A.w) * trA.w;
                float bB0 = (1.f - e1B.x) * trB.x, bB1 = (1.f - e1B.y) * trB.y;
                float bB2 = (1.f - e1B.z) * trB.z, bB3 = (1.f - e1B.w) * trB.w;
                float sA0 = e1A.x * x1A, sA1 = e1A.y * x1A, sA2 = e1A.z * x1A, sA3 = e1A.w * x1A;
                float sB0 = e1B.x * x1B, sB1 = e1B.y * x1B, sB2 = e1B.z * x1B, sB3 = e1B.w * x1B;
                float pA0 = x2A * (wA.x + aA.x * bA0) + x2B * (wB.x + aB.x * bB0);
                float pA1 = x2A * (wA.y + aA.y * bA1) + x2B * (wB.y + aB.y * bB1);
                float pA2 = x2A * (wA.z + aA.z * bA2) + x2B * (wB.z + aB.z * bB2);
                float pA3 = x2A * (wA.w + aA.w * bA3) + x2B * (wB.w + aB.w * bB3);
                float pB0 = x2A * (aA.x * sA0) + x2B * (aB.x * sB0);
                float pB1 = x2A * (aA.y * sA1) + x2B * (aB.y * sB1);
                float pB2 = x2A * (aA.z * sA2) + x2B * (aB.z * sB2);
                float pB3 = x2A * (aA.w * sA3) + x2B * (aB.w * sB3);
                float hbp = fmaxf(fmaxf(fmaxf(bA0, bA1), fmaxf(bA2, bA3)),
                                  fmaxf(fmaxf(bB0, bB1), fmaxf(bB2, bB3)));
                float hbn = fminf(fminf(fminf(bA0, bA1), fminf(bA2, bA3)),
                                  fminf(fminf(bB0, bB1), fminf(bB2, bB3)));
                float hsp = fmaxf(fmaxf(fmaxf(sA0, sA1), fmaxf(sA2, sA3)),
                                  fmaxf(fmaxf(sB0, sB1), fmaxf(sB2, sB3)));
                hsp = fmaxf(hsp, 0.f);
                float hsn = fminf(fminf(fminf(sA0, sA1), fminf(sA2, sA3)),
                                  fminf(fminf(sB0, sB1), fminf(sB2, sB3)));
                hsn = fminf(hsn, 0.f);
                pA0 = wsum(pA0); pA1 = wsum(pA1); pA2 = wsum(pA2); pA3 = wsum(pA3);
                pB0 = wsum(pB0); pB1 = wsum(pB1); pB2 = wsum(pB2); pB3 = wsum(pB3);
                hbp = wmaxr(hbp); hsp = wmaxr(hsp);
                hbn = wminr(hbn); hsn = wminr(hsn);
                if ((tid & 63) == 0) {
                    float* wr = wred[wi];
                    wr[0] = pA0; wr[1] = pA1; wr[2] = pA2; wr[3] = pA3;
                    wr[4] = pB0; wr[5] = pB1; wr[6] = pB2; wr[7] = pB3;
                    wr[8] = hbp; wr[9] = hsp; wr[10] = hbn; wr[11] = hsn;
                }
            }
            // rotate rings
            e0A = e1A; e0B = e1B; e1A = e2A; e1B = e2B; e2A = e3A; e2B = e3B;
            xPA = x1A; xPB = x1B; x1A = x2A; x1B = x2B;
            if (t + 3 < BATCH) {
                x2A = x[(size_t)(t + 3) * IN_F + r0];
                x2B = x[(size_t)(t + 3) * IN_F + r1];
            }
        }
        __syncthreads();
    }
}

extern "C" void kernel_launch(void* const* d_in, const int* in_sizes, int n_in,
                              void* d_out, int out_size, void* d_ws, size_t ws_size,
                              hipStream_t stream) {
    const float* x     = (const float*)d_in[0];
    const float* eta   = (const float*)d_in[1];
    const float* w     = (const float*)d_in[2];
    // d_in[3] = b: scalar added to all logits -> cancels in softmax, unused
    const float* alpha = (const float*)d_in[4];
    float* out = (float*)d_out;

    const size_t msb_bytes = (size_t)BATCH * NWG * sizeof(unsigned int);  // 256 KiB
    int bshift = 5;  // 128B line-disjoint slots if workspace allows
    while (bshift > 0 &&
           msb_bytes + (((size_t)BATCH * NWG * sizeof(unsigned int)) << bshift) > ws_size)
        --bshift;
    unsigned int* msbuf = (unsigned int*)d_ws;
    unsigned int* bcast = (unsigned int*)((char*)d_ws + msb_bytes);

    hipMemsetAsync(d_ws, 0xFF,
                   msb_bytes + (((size_t)BATCH * NWG * sizeof(unsigned int)) << bshift),
                   stream);

    plastic_scan_kernel<<<dim3(NWG), dim3(TPB), 0, stream>>>(
        x, eta, w, alpha, out, msbuf, bcast, bshift);
}